// Round 2
// baseline (256.475 us; speedup 1.0000x reference)
//
#include <hip/hip_runtime.h>

// Problem constants (from reference): S=7, B=2, C=20, N=30, batch=16384
#define NCH 30
#define RANK_LIMIT 49          // S*S
#define L_COORD 5.0f
#define L_NOOBJ 0.5f

#define ROWS_PER_TILE 256
#define F4_PER_TILE (ROWS_PER_TILE * NCH / 4)   // 1920 float4 per tile per array

// ---------------------------------------------------------------------------
// Kernel 1 (v2): no-object confidence loss, fully-coalesced float4 streaming.
// R1 showed scattered scalar loads (120B stride) limit us to 1.6 TB/s.
// Layout trick: lcm(30,4)=60 floats = 15 float4 per 2 rows, so within each
// 2-row group the needed channels sit at fixed (float4-index, component):
//   row0 ch4 -> f4 #1 comp .x ; row0 ch9 -> f4 #2 comp .y
//   row1 ch4 -> f4 #8 comp .z ; row1 ch9 -> f4 #9 comp .w
// Phase 1 streams the target tile, scattering t4/t9 into LDS (2 KB).
// Phase 2 streams the pred tile, accumulating gated squared diffs.
// ---------------------------------------------------------------------------
__global__ __launch_bounds__(256) void noobj_kernel(const float4* __restrict__ pv,
                                                    const float4* __restrict__ tv,
                                                    float* __restrict__ ws) {
    __shared__ float s_t4[ROWS_PER_TILE];
    __shared__ float s_t9[ROWS_PER_TILE];
    const long base4 = (long)blockIdx.x * F4_PER_TILE;

    // Phase 1: stream target tile, extract ch4/ch9 per row into LDS.
    for (int i = threadIdx.x; i < F4_PER_TILE; i += 256) {
        float4 v = tv[base4 + i];
        int pair = i / 15;              // 2-row group within tile (0..127)
        int k = i - pair * 15;          // float4 slot within the 60-float group
        int r0 = 2 * pair;
        if (k == 1)      s_t4[r0]     = v.x;
        else if (k == 2) s_t9[r0]     = v.y;
        else if (k == 8) s_t4[r0 + 1] = v.z;
        else if (k == 9) s_t9[r0 + 1] = v.w;
    }
    __syncthreads();

    // Phase 2: stream pred tile, accumulate (p-t)^2 for noobj rows.
    float acc = 0.0f;
    for (int i = threadIdx.x; i < F4_PER_TILE; i += 256) {
        float4 v = pv[base4 + i];
        int pair = i / 15;
        int k = i - pair * 15;
        int r0 = 2 * pair;
        if (k == 1) {
            float t4 = s_t4[r0];
            if (!(t4 > 0.0f)) { float d = v.x - t4; acc += d * d; }
        } else if (k == 2) {
            float t4 = s_t4[r0];
            if (!(t4 > 0.0f)) { float d = v.y - s_t9[r0]; acc += d * d; }
        } else if (k == 8) {
            float t4 = s_t4[r0 + 1];
            if (!(t4 > 0.0f)) { float d = v.z - t4; acc += d * d; }
        } else if (k == 9) {
            float t4 = s_t4[r0 + 1];
            if (!(t4 > 0.0f)) { float d = v.w - s_t9[r0 + 1]; acc += d * d; }
        }
    }

    // wave (64-lane) reduction, then cross-wave via LDS, one atomic per block
    #pragma unroll
    for (int off = 32; off > 0; off >>= 1)
        acc += __shfl_down(acc, off, 64);
    __shared__ float s[4];
    int lane = threadIdx.x & 63;
    int wid  = threadIdx.x >> 6;
    if (lane == 0) s[wid] = acc;
    __syncthreads();
    if (threadIdx.x == 0)
        atomicAdd(ws, s[0] + s[1] + s[2] + s[3]);
}

// ---------------------------------------------------------------------------
// Per-row "selected" bbox loss — faithful port of the reference including its
// bugs: x2y2 built from the already-transformed xy; lambda_coord only on the
// x / sqrt(w) terms; selected loss sums l1+l2+l3+IoU; argmax keeps first max.
// ---------------------------------------------------------------------------
__device__ inline float sel_loss(const float* __restrict__ p,
                                 const float* __restrict__ t, int row) {
    const float invS = 1.0f / 7.0f;
    int b0 = row * NCH;
    float tot0 = 0.f, tot1 = 0.f, iou0 = 0.f, iou1 = 0.f;
    #pragma unroll
    for (int j = 0; j < 2; ++j) {
        int o = b0 + 5 * j;
        float px = p[o + 0], py = p[o + 1], pw = p[o + 2], ph = p[o + 3], pc = p[o + 4];
        float tx = t[o + 0], ty = t[o + 1], tw = t[o + 2], th = t[o + 3], tc = t[o + 4];
        float pxy0 = px * invS - 0.5f * pw;
        float pxy1 = py * invS - 0.5f * ph;
        float p2x  = pxy0 * invS + 0.5f * pw;
        float p2y  = pxy1 * invS + 0.5f * ph;
        float txy0 = tx * invS - 0.5f * tw;
        float txy1 = ty * invS - 0.5f * th;
        float t2x  = txy0 * invS + 0.5f * tw;
        float t2y  = txy1 * invS + 0.5f * th;
        float d0 = txy0 - pxy0, d1 = txy1 - pxy1;
        float l1 = L_COORD * d0 * d0 + d1 * d1;
        float s0 = sqrtf(t2x) - sqrtf(p2x);
        float s1 = sqrtf(t2y) - sqrtf(p2y);
        float l2 = L_COORD * s0 * s0 + s1 * s1;
        float dc = tc - pc;
        float l3 = dc * dc;
        float ltx = fmaxf(pxy0, txy0), lty = fmaxf(pxy1, txy1);
        float rbx = fminf(p2x, t2x),   rby = fminf(p2y, t2y);
        float wx  = fmaxf(rbx - ltx, 0.0f);
        float wy  = fmaxf(rby - lty, 0.0f);
        float inter  = wx * wy;
        float area_p = (p2x - pxy0) * (p2y - pxy1);
        float area_t = (t2x - txy0) * (t2y - txy1);
        float io = inter / (area_p + area_t - inter);
        float tt = l1 + l2 + l3 + io;
        if (j == 0) { iou0 = io; tot0 = tt; }
        else        { iou1 = io; tot1 = tt; }
    }
    return (iou1 > iou0) ? tot1 : tot0;   // argmax keeps FIRST max
}

// ---------------------------------------------------------------------------
// Kernel 2: ordered scan for the bbox loss (unchanged from R1 — correct and
// off the critical path). Single block; ballot-scan for exact global ranks;
// uniform early exit once 49 objects consumed (~1 chunk at 25% density).
// ---------------------------------------------------------------------------
__global__ __launch_bounds__(256) void bbox_kernel(const float* __restrict__ p,
                                                   const float* __restrict__ t,
                                                   const float* __restrict__ ws,
                                                   float* __restrict__ out, int M) {
    __shared__ int   s_wcnt[4];
    __shared__ int   s_base;
    __shared__ float s_part[4];
    if (threadIdx.x == 0) s_base = 0;
    __syncthreads();

    float local = 0.0f;
    for (int start = 0; start < M; start += 256) {
        int row = start + (int)threadIdx.x;
        bool obj = false;
        if (row < M) obj = t[row * NCH + 4] > 0.0f;

        unsigned long long mask = __ballot(obj);
        int lane = threadIdx.x & 63;
        int wid  = threadIdx.x >> 6;
        if (lane == 0) s_wcnt[wid] = __popcll(mask);
        __syncthreads();

        int base = s_base;
        int off = 0;
        for (int w = 0; w < wid; ++w) off += s_wcnt[w];
        int rank = base + off + __popcll(mask & ((1ULL << lane) - 1ULL));
        if (obj && rank < RANK_LIMIT) local += sel_loss(p, t, row);
        __syncthreads();

        if (threadIdx.x == 0)
            s_base = base + s_wcnt[0] + s_wcnt[1] + s_wcnt[2] + s_wcnt[3];
        __syncthreads();
        if (s_base >= RANK_LIMIT) break;
    }

    #pragma unroll
    for (int o = 32; o > 0; o >>= 1)
        local += __shfl_down(local, o, 64);
    int lane = threadIdx.x & 63;
    int wid  = threadIdx.x >> 6;
    if (lane == 0) s_part[wid] = local;
    __syncthreads();
    if (threadIdx.x == 0) {
        float bbox = s_part[0] + s_part[1] + s_part[2] + s_part[3];
        out[0] = bbox + L_NOOBJ * ws[0];
    }
}

extern "C" void kernel_launch(void* const* d_in, const int* in_sizes, int n_in,
                              void* d_out, int out_size, void* d_ws, size_t ws_size,
                              hipStream_t stream) {
    const float* pred = (const float*)d_in[0];
    const float* targ = (const float*)d_in[1];
    float* out = (float*)d_out;
    float* acc = (float*)d_ws;

    int M = in_sizes[0] / NCH;           // 16384*49 = 802816 rows (divisible by 256)
    int tiles = M / ROWS_PER_TILE;       // 3136 tiles

    // ws is re-poisoned to 0xAA before every call — zero the accumulator.
    hipMemsetAsync(d_ws, 0, 16, stream);

    noobj_kernel<<<tiles, 256, 0, stream>>>((const float4*)pred, (const float4*)targ, acc);
    bbox_kernel<<<1, 256, 0, stream>>>(pred, targ, acc, out, M);
}

// Round 3
// 209.935 us; speedup vs baseline: 1.2217x; 1.2217x over previous
//
#include <hip/hip_runtime.h>

// Problem constants (from reference): S=7, B=2, C=20, N=30, batch=16384
#define NCH 30
#define RANK_LIMIT 49          // S*S
#define L_COORD 5.0f
#define L_NOOBJ 0.5f

// Streaming geometry: M=802816 rows * 30 floats / 4 = 6,021,120 float4.
// 980 blocks * 256 threads * unroll 8 * 3 outer iters = 6,021,120 exactly.
#define NB 980
#define UNROLL 8
#define OUTER 3

// ---------------------------------------------------------------------------
// Kernel 1 (v3): m13-style float4 streamer. R2 failed (0.8 TB/s) from block
// churn + non-unrolled loads + LDS/barrier in the stream. Here: persistent
// blocks, 16 independent dwordx4 loads in flight per iteration, no LDS/barrier
// until the final block reduce, per-block partial (no atomics, no memset).
//
// Channel decode: float4 index i covers floats [4i,4i+4). With 60-float
// (2-row) groups: pair=i/15, k=i%15.
//   k==1 -> row 2p   ch4..7 : t4=vt.x (gate+term), p4=vp.x
//   k==2 -> row 2p   ch8..11: t9=vt.y, p9=vp.y, gate t4 = ts[60p+4]
//   k==8 -> row 2p+1 ch2..5 : t4=vt.z (gate+term), p4=vp.z
//   k==9 -> row 2p+1 ch6..9 : t9=vt.w, p9=vp.w, gate t4 = ts[60p+34]
// ---------------------------------------------------------------------------
__global__ __launch_bounds__(256) void noobj_kernel(const float4* __restrict__ pv,
                                                    const float4* __restrict__ tv,
                                                    const float* __restrict__ ts,
                                                    float* __restrict__ ws) {
    float acc = 0.0f;
    int base = blockIdx.x * (256 * UNROLL) + threadIdx.x;
    const int step = NB * 256 * UNROLL;          // 2,007,040

    for (int outer = 0; outer < OUTER; ++outer, base += step) {
        float4 vp[UNROLL], vt[UNROLL];
        float  gate[UNROLL];
        int    kk[UNROLL];

        // Issue all vector loads first — fully independent.
        #pragma unroll
        for (int u = 0; u < UNROLL; ++u) {
            int i = base + u * 256;
            vp[u] = pv[i];
            vt[u] = tv[i];
        }
        // Independent scalar gate loads for k in {2,9} (address from index only).
        #pragma unroll
        for (int u = 0; u < UNROLL; ++u) {
            int i = base + u * 256;
            int pair = i / 15;                   // magic-mul
            int k = i - pair * 15;
            kk[u] = k;
            gate[u] = 1.0f;                      // default: no contribution path
            if (k == 2)      gate[u] = ts[pair * 60 + 4];
            else if (k == 9) gate[u] = ts[pair * 60 + 34];
        }
        // Consume.
        #pragma unroll
        for (int u = 0; u < UNROLL; ++u) {
            int k = kk[u];
            if (k == 1) {
                float t4 = vt[u].x;
                if (!(t4 > 0.0f)) { float d = vp[u].x - t4; acc += d * d; }
            } else if (k == 2) {
                if (!(gate[u] > 0.0f)) { float d = vp[u].y - vt[u].y; acc += d * d; }
            } else if (k == 8) {
                float t4 = vt[u].z;
                if (!(t4 > 0.0f)) { float d = vp[u].z - t4; acc += d * d; }
            } else if (k == 9) {
                if (!(gate[u] > 0.0f)) { float d = vp[u].w - vt[u].w; acc += d * d; }
            }
        }
    }

    // wave (64-lane) reduction, cross-wave via LDS, per-block partial to ws.
    #pragma unroll
    for (int off = 32; off > 0; off >>= 1)
        acc += __shfl_down(acc, off, 64);
    __shared__ float s[4];
    int lane = threadIdx.x & 63;
    int wid  = threadIdx.x >> 6;
    if (lane == 0) s[wid] = acc;
    __syncthreads();
    if (threadIdx.x == 0)
        ws[blockIdx.x] = s[0] + s[1] + s[2] + s[3];
}

// ---------------------------------------------------------------------------
// Per-row "selected" bbox loss — faithful port of the reference including its
// bugs: x2y2 built from the already-transformed xy; lambda_coord only on the
// x / sqrt(w) terms; selected loss sums l1+l2+l3+IoU; argmax keeps first max.
// ---------------------------------------------------------------------------
__device__ inline float sel_loss(const float* __restrict__ p,
                                 const float* __restrict__ t, int row) {
    const float invS = 1.0f / 7.0f;
    int b0 = row * NCH;
    float tot0 = 0.f, tot1 = 0.f, iou0 = 0.f, iou1 = 0.f;
    #pragma unroll
    for (int j = 0; j < 2; ++j) {
        int o = b0 + 5 * j;
        float px = p[o + 0], py = p[o + 1], pw = p[o + 2], ph = p[o + 3], pc = p[o + 4];
        float tx = t[o + 0], ty = t[o + 1], tw = t[o + 2], th = t[o + 3], tc = t[o + 4];
        float pxy0 = px * invS - 0.5f * pw;
        float pxy1 = py * invS - 0.5f * ph;
        float p2x  = pxy0 * invS + 0.5f * pw;
        float p2y  = pxy1 * invS + 0.5f * ph;
        float txy0 = tx * invS - 0.5f * tw;
        float txy1 = ty * invS - 0.5f * th;
        float t2x  = txy0 * invS + 0.5f * tw;
        float t2y  = txy1 * invS + 0.5f * th;
        float d0 = txy0 - pxy0, d1 = txy1 - pxy1;
        float l1 = L_COORD * d0 * d0 + d1 * d1;
        float s0 = sqrtf(t2x) - sqrtf(p2x);
        float s1 = sqrtf(t2y) - sqrtf(p2y);
        float l2 = L_COORD * s0 * s0 + s1 * s1;
        float dc = tc - pc;
        float l3 = dc * dc;
        float ltx = fmaxf(pxy0, txy0), lty = fmaxf(pxy1, txy1);
        float rbx = fminf(p2x, t2x),   rby = fminf(p2y, t2y);
        float wx  = fmaxf(rbx - ltx, 0.0f);
        float wy  = fmaxf(rby - lty, 0.0f);
        float inter  = wx * wy;
        float area_p = (p2x - pxy0) * (p2y - pxy1);
        float area_t = (t2x - txy0) * (t2y - txy1);
        float io = inter / (area_p + area_t - inter);
        float tt = l1 + l2 + l3 + io;
        if (j == 0) { iou0 = io; tot0 = tt; }
        else        { iou1 = io; tot1 = tt; }
    }
    return (iou1 > iou0) ? tot1 : tot0;   // argmax keeps FIRST max
}

// ---------------------------------------------------------------------------
// Kernel 2: ordered ballot-scan for the bbox loss + final combine. Single
// block; uniform early exit once 49 objects consumed (~1 chunk at 25%
// density). Also sums the NB noobj partials (replaces memset+atomics).
// ---------------------------------------------------------------------------
__global__ __launch_bounds__(256) void bbox_kernel(const float* __restrict__ p,
                                                   const float* __restrict__ t,
                                                   const float* __restrict__ ws,
                                                   float* __restrict__ out, int M) {
    __shared__ int   s_wcnt[4];
    __shared__ int   s_base;
    __shared__ float s_part[4];
    if (threadIdx.x == 0) s_base = 0;
    __syncthreads();

    float local = 0.0f;
    for (int start = 0; start < M; start += 256) {
        int row = start + (int)threadIdx.x;
        bool obj = false;
        if (row < M) obj = t[row * NCH + 4] > 0.0f;

        unsigned long long mask = __ballot(obj);
        int lane = threadIdx.x & 63;
        int wid  = threadIdx.x >> 6;
        if (lane == 0) s_wcnt[wid] = __popcll(mask);
        __syncthreads();

        int base = s_base;
        int off = 0;
        for (int w = 0; w < wid; ++w) off += s_wcnt[w];
        int rank = base + off + __popcll(mask & ((1ULL << lane) - 1ULL));
        if (obj && rank < RANK_LIMIT) local += sel_loss(p, t, row);
        __syncthreads();

        if (threadIdx.x == 0)
            s_base = base + s_wcnt[0] + s_wcnt[1] + s_wcnt[2] + s_wcnt[3];
        __syncthreads();
        if (s_base >= RANK_LIMIT) break;
    }

    // fold the noobj partials in (scaled), then block-reduce everything once
    for (int i = threadIdx.x; i < NB; i += 256)
        local += L_NOOBJ * ws[i];

    #pragma unroll
    for (int o = 32; o > 0; o >>= 1)
        local += __shfl_down(local, o, 64);
    int lane = threadIdx.x & 63;
    int wid  = threadIdx.x >> 6;
    if (lane == 0) s_part[wid] = local;
    __syncthreads();
    if (threadIdx.x == 0)
        out[0] = s_part[0] + s_part[1] + s_part[2] + s_part[3];
}

extern "C" void kernel_launch(void* const* d_in, const int* in_sizes, int n_in,
                              void* d_out, int out_size, void* d_ws, size_t ws_size,
                              hipStream_t stream) {
    const float* pred = (const float*)d_in[0];
    const float* targ = (const float*)d_in[1];
    float* out = (float*)d_out;
    float* partials = (float*)d_ws;      // NB floats; all written before read

    int M = in_sizes[0] / NCH;           // 802816 rows

    noobj_kernel<<<NB, 256, 0, stream>>>((const float4*)pred, (const float4*)targ,
                                         targ, partials);
    bbox_kernel<<<1, 256, 0, stream>>>(pred, targ, partials, out, M);
}